// Round 7
// baseline (571.340 us; speedup 1.0000x reference)
//
#include <hip/hip_runtime.h>

typedef unsigned short u16;
typedef unsigned int u32;
typedef __bf16 bf16x8 __attribute__((ext_vector_type(8)));
typedef float floatx4 __attribute__((ext_vector_type(4)));
typedef u16 u16x4 __attribute__((ext_vector_type(4)));
typedef u16 u16x8 __attribute__((ext_vector_type(8)));
typedef u32 u32x2 __attribute__((ext_vector_type(2)));

#define B_ 4
#define T_ 1024
#define C_ 2048
#define H_ 32
#define HD_ 64

__device__ __forceinline__ float b2f(u16 u) {
    u32 x = ((u32)u) << 16;
    return __builtin_bit_cast(float, x);
}
__device__ __forceinline__ u16 f2b(float f) {          // RNE (epilogues)
    u32 i = __builtin_bit_cast(u32, f);
    u32 r = (i + 0x7FFFu + ((i >> 16) & 1u)) >> 16;
    return (u16)r;
}
// pack two fp32 -> two bf16 (round-half-up), 2 adds + 1 v_perm_b32
__device__ __forceinline__ u32 pack2(float a, float b) {
    const u32 ua = __builtin_bit_cast(u32, a) + 0x8000u;
    const u32 ub = __builtin_bit_cast(u32, b) + 0x8000u;
    return __builtin_amdgcn_perm(ub, ua, 0x07060302u);  // [ub_hi : ua_hi]
}

#define GLOAD16(gp, lp) __builtin_amdgcn_global_load_lds( \
    (const __attribute__((address_space(1))) void*)(gp),  \
    (__attribute__((address_space(3))) void*)(lp), 16, 0, 0)

// ---------------------------------------------------------------------------
// fp32 -> bf16 elementwise convert (HBM-bound prework)
// ---------------------------------------------------------------------------
__global__ __launch_bounds__(256) void convert_bf16(const float* __restrict__ src,
                                                    u16* __restrict__ dst, int n4) {
    const int stride = gridDim.x * 256;
    for (int i = blockIdx.x * 256 + threadIdx.x; i < n4; i += stride) {
        const floatx4 v = *(const floatx4*)(src + (size_t)i * 4);
        const u32x2 h = {pack2(v.x, v.y), pack2(v.z, v.w)};
        *(u32x2*)(dst + (size_t)i * 4) = h;
    }
}

// ---------------------------------------------------------------------------
// V (B,H,T,hd) -> V^T (B,H,hd,T), one 64x64 tile per block via LDS.
// ---------------------------------------------------------------------------
__global__ __launch_bounds__(256) void transpose_v(const u16* __restrict__ vin,
                                                   u16* __restrict__ vout) {
    __shared__ u16 L[64][72];
    const int tid = threadIdx.x;
    const int bh = blockIdx.y, t0 = blockIdx.x * 64;
    const u16* src = vin + (size_t)bh * (T_ * HD_) + (size_t)t0 * HD_;
    const int r = tid >> 2, c = (tid & 3) * 16;
    *(u16x8*)&L[r][c]     = *(const u16x8*)(src + r * HD_ + c);
    *(u16x8*)&L[r][c + 8] = *(const u16x8*)(src + r * HD_ + c + 8);
    __syncthreads();
    const int d = tid >> 2, ts = (tid & 3) * 16;
    u16x8 o0, o1;
#pragma unroll
    for (int t = 0; t < 8; t++) o0[t] = L[ts + t][d];
#pragma unroll
    for (int t = 0; t < 8; t++) o1[t] = L[ts + 8 + t][d];
    u16* dst = vout + (size_t)bh * (T_ * HD_) + (size_t)d * T_ + t0 + ts;
    *(u16x8*)dst = o0;
    *(u16x8*)(dst + 8) = o1;
}

// ---------------------------------------------------------------------------
// GEMM: C[m,n] = sum_k A[m,k] * W[n,k] + bias[n]   (A, W bf16 row-major)
// m97 structure + XOR-swizzled LDS (verified round 6).
// MODE 0: epilogue bias + RoPE + scatter to q/k/v (B,H,T,hd) bf16.
// MODE 1: epilogue bias, fp32 row-major store.
// ---------------------------------------------------------------------------
template <int MODE>
__global__ __launch_bounds__(256) void gemm_bt(const u16* __restrict__ A,
                                               const u16* __restrict__ W,
                                               const float* __restrict__ bias,
                                               const float* __restrict__ rope,
                                               void* __restrict__ o0v,
                                               u16* __restrict__ o1,
                                               u16* __restrict__ o2) {
    const int Kdim = 2048;
    __shared__ __align__(16) u16 As[128 * 64];
    __shared__ __align__(16) u16 Bs[128 * 64];

    const int tid = threadIdx.x;
    const int w = tid >> 6, lane = tid & 63;
    const int wr = w >> 1, wc = w & 1;
    const int quad = lane >> 4, l15 = lane & 15;
    const int mBase = blockIdx.y * 128, nBase = blockIdx.x * 128;

    floatx4 acc[4][4] = {};

    const int lrow = lane >> 3;
    const int lcol = ((lane & 7) ^ lrow) * 8;
    const u16* Ap = A + (size_t)(mBase + lrow) * Kdim + lcol;
    const u16* Wp = W + (size_t)(nBase + lrow) * Kdim + lcol;

    const int xk = l15 & 7;   // read-side XOR key (row & 7)

    for (int k0 = 0; k0 < Kdim; k0 += 64) {
#pragma unroll
        for (int i = 0; i < 4; i++) {
            const int c = i * 4 + w;
            GLOAD16(Ap + (size_t)c * 8 * Kdim + k0, &As[c * 512]);
            GLOAD16(Wp + (size_t)c * 8 * Kdim + k0, &Bs[c * 512]);
        }
        __syncthreads();
#pragma unroll
        for (int ks = 0; ks < 64; ks += 32) {
            bf16x8 af[4], bfr[4];
#pragma unroll
            for (int i = 0; i < 4; i++) {
                const int co = (((ks >> 3) + quad) ^ xk) * 8;
                af[i] = *(const bf16x8*)&As[(wr * 64 + i * 16 + l15) * 64 + co];
            }
#pragma unroll
            for (int j = 0; j < 4; j++) {
                const int co = (((ks >> 3) + quad) ^ xk) * 8;
                bfr[j] = *(const bf16x8*)&Bs[(wc * 64 + j * 16 + l15) * 64 + co];
            }
#pragma unroll
            for (int i = 0; i < 4; i++)
#pragma unroll
                for (int j = 0; j < 4; j++)
                    acc[i][j] = __builtin_amdgcn_mfma_f32_16x16x32_bf16(af[i], bfr[j], acc[i][j], 0, 0, 0);
        }
        __syncthreads();
    }

    const int nq = nBase + wc * 64;
    float bv[4];
#pragma unroll
    for (int j = 0; j < 4; j++) bv[j] = bias[nq + j * 16 + l15];

    if (MODE == 0) {
        const int region = nq >> 11;            // 0=q 1=k 2=v (tile never straddles)
        const int h = (nq & 2047) >> 6;
        const int d = l15;
        u16* dst = (region == 0) ? (u16*)o0v : ((region == 1) ? o1 : o2);
#pragma unroll
        for (int i = 0; i < 4; i++) {
#pragma unroll
            for (int r = 0; r < 4; r++) {
                const int m = mBase + wr * 64 + i * 16 + quad * 4 + r;
                const int b = m >> 10, t = m & 1023;
                float v0 = acc[i][0][r] + bv[0];
                float v1 = acc[i][1][r] + bv[1];
                float v2 = acc[i][2][r] + bv[2];
                float v3 = acc[i][3][r] + bv[3];
                const size_t base = ((size_t)(b * H_ + h) * T_ + t) * HD_;
                if (region < 2) {
                    const float cz = rope[t * 32 + d * 2];
                    const float sz = rope[t * 32 + d * 2 + 1];
                    const float n0 = v0 * cz - v1 * sz;
                    const float n1 = v1 * cz + v0 * sz;
                    dst[base + d] = f2b(n0);
                    dst[base + 16 + d] = f2b(n1);
                } else {
                    dst[base + d] = f2b(v0);
                    dst[base + 16 + d] = f2b(v1);
                }
                dst[base + 32 + d] = f2b(v2);
                dst[base + 48 + d] = f2b(v3);
            }
        }
    } else {
        float* outf = (float*)o0v;
#pragma unroll
        for (int i = 0; i < 4; i++)
#pragma unroll
            for (int r = 0; r < 4; r++) {
                const int m = mBase + wr * 64 + i * 16 + quad * 4 + r;
                const size_t o = (size_t)m * 2048 + nq;
#pragma unroll
                for (int j = 0; j < 4; j++)
                    outf[o + j * 16 + l15] = acc[i][j][r] + bv[j];
            }
    }
}

// ---------------------------------------------------------------------------
// MFMA flash attention, barrier-free k-loop.
// Block = (b,h) x 64-query tile, 4 waves x 16 q-rows. V^T precomputed in
// global (B,H,hd,T) so both K (A of S^T=K@Q^T) and V^T (A of O^T=V^T@P)
// fragments are contiguous 16B global loads. P^T round-trips wave-private
// LDS (lgkmcnt-ordered within the wave, no __syncthreads anywhere in loop).
// ---------------------------------------------------------------------------
#define VT_STR 72

__global__ __launch_bounds__(256) void attn_mfma(const u16* __restrict__ qT,
                                                 const u16* __restrict__ kT,
                                                 const u16* __restrict__ vTt,
                                                 u16* __restrict__ ctx) {
    __shared__ __align__(16) u16 Pt[4 * 16 * VT_STR];    // per-wave P^T: [q][key]

    const int tid = threadIdx.x;
    const int w = tid >> 6, lane = tid & 63;
    const int quad = lane >> 4, l15 = lane & 15;
    const int qt = 15 - (int)blockIdx.x;   // big tiles dispatch first
    const int bh = blockIdx.y;
    const size_t headBase = (size_t)bh * (T_ * HD_);

    bf16x8 qf[2];
    {
        const u16* qrow = qT + headBase + ((size_t)qt * 64 + w * 16 + l15) * HD_ + quad * 8;
        qf[0] = __builtin_bit_cast(bf16x8, *(const u16x8*)(qrow));
        qf[1] = __builtin_bit_cast(bf16x8, *(const u16x8*)(qrow + 32));
    }

    u16* myPt = &Pt[w * 16 * VT_STR];
    float m_i = -1e30f, l_i = 0.f;
    floatx4 oacc[4] = {};

    // V^T rows this lane reads (fixed across k-tiles): hd = mi*16 + l15
    const u16* vtBase = vTt + headBase + (size_t)l15 * T_ + (size_t)quad * 8;

    for (int kt = 0; kt <= qt; kt++) {
        const u16* kp = kT + headBase + (size_t)kt * 64 * HD_;

        // S^T = K @ Q^T : A=K frags direct from global
        floatx4 st[4] = {};
#pragma unroll
        for (int mi = 0; mi < 4; mi++) {
            const u16* krow = kp + (mi * 16 + l15) * HD_ + quad * 8;
            const bf16x8 kf0 = __builtin_bit_cast(bf16x8, *(const u16x8*)(krow));
            const bf16x8 kf1 = __builtin_bit_cast(bf16x8, *(const u16x8*)(krow + 32));
            st[mi] = __builtin_amdgcn_mfma_f32_16x16x32_bf16(kf0, qf[0], st[mi], 0, 0, 0);
            st[mi] = __builtin_amdgcn_mfma_f32_16x16x32_bf16(kf1, qf[1], st[mi], 0, 0, 0);
        }

        float pmax = -1e30f;
#pragma unroll
        for (int mi = 0; mi < 4; mi++)
#pragma unroll
            for (int r = 0; r < 4; r++) {
                float sv = st[mi][r] * 0.125f;
                if (kt == qt && (mi * 16 + quad * 4 + r) > (w * 16 + l15)) sv = -1e30f;
                st[mi][r] = sv;
                pmax = fmaxf(pmax, sv);
            }
        pmax = fmaxf(pmax, __shfl_xor(pmax, 16, 64));
        pmax = fmaxf(pmax, __shfl_xor(pmax, 32, 64));
        const float mnew = fmaxf(m_i, pmax);
        const float alpha = __expf(m_i - mnew);
        m_i = mnew;

        float psum = 0.f;
#pragma unroll
        for (int mi = 0; mi < 4; mi++) {
            u16x4 pk;
#pragma unroll
            for (int r = 0; r < 4; r++) {
                const float p = __expf(st[mi][r] - mnew);
                psum += p;
                pk[r] = f2b(p);
            }
            *(u16x4*)&myPt[l15 * VT_STR + mi * 16 + quad * 4] = pk;
        }
        psum += __shfl_xor(psum, 16, 64);
        psum += __shfl_xor(psum, 32, 64);
        l_i = l_i * alpha + psum;

#pragma unroll
        for (int mi = 0; mi < 4; mi++) oacc[mi] *= alpha;

        // O^T += V^T @ P : A=V^T frags direct from global, B=P (wave LDS)
        bf16x8 pf[2];
        pf[0] = __builtin_bit_cast(bf16x8, *(const u16x8*)&myPt[l15 * VT_STR + quad * 8]);
        pf[1] = __builtin_bit_cast(bf16x8, *(const u16x8*)&myPt[l15 * VT_STR + 32 + quad * 8]);
        const u16* vk = vtBase + kt * 64;
#pragma unroll
        for (int mi = 0; mi < 4; mi++) {
            const u16* vrow = vk + (size_t)mi * 16 * T_;
            const bf16x8 vf0 = __builtin_bit_cast(bf16x8, *(const u16x8*)(vrow));
            const bf16x8 vf1 = __builtin_bit_cast(bf16x8, *(const u16x8*)(vrow + 32));
            oacc[mi] = __builtin_amdgcn_mfma_f32_16x16x32_bf16(vf0, pf[0], oacc[mi], 0, 0, 0);
            oacc[mi] = __builtin_amdgcn_mfma_f32_16x16x32_bf16(vf1, pf[1], oacc[mi], 0, 0, 0);
        }
    }

    const float inv = 1.0f / l_i;
    const int b = bh >> 5, h = bh & 31;
    const int t = qt * 64 + w * 16 + l15;
    u16* cp = ctx + ((size_t)(b * T_ + t)) * C_ + h * HD_;
#pragma unroll
    for (int mi = 0; mi < 4; mi++) {
        const u16x4 ov = {f2b(oacc[mi][0] * inv), f2b(oacc[mi][1] * inv),
                          f2b(oacc[mi][2] * inv), f2b(oacc[mi][3] * inv)};
        *(u16x4*)(cp + mi * 16 + quad * 4) = ov;
    }
}

extern "C" void kernel_launch(void* const* d_in, const int* in_sizes, int n_in,
                              void* d_out, int out_size, void* d_ws, size_t ws_size,
                              hipStream_t stream) {
    const float* x      = (const float*)d_in[0];
    const float* rope   = (const float*)d_in[3];
    const float* Wqkv_w = (const float*)d_in[4];
    const float* Wqkv_b = (const float*)d_in[5];
    const float* out_w  = (const float*)d_in[6];
    const float* out_b  = (const float*)d_in[7];
    float* out = (float*)d_out;

    // ws layout (u16 elems), total 100.7 MB:
    //   xb 8.39M | wqkvb 12.58M | outwb 4.19M | qT 8.39M | kT 8.39M | vT 8.39M
    //   ctx aliases xb (x dead after gemm0); vTt aliases wqkvb (dead after gemm0)
    const size_t headElems = (size_t)B_ * H_ * T_ * HD_;     // 8388608
    u16* xb    = (u16*)d_ws;
    u16* wqkvb = xb + headElems;
    u16* outwb = wqkvb + 12582912;
    u16* qTp   = outwb + 4194304;
    u16* kTp   = qTp + headElems;
    u16* vTp   = kTp + headElems;
    u16* ctx   = xb;
    u16* vTt   = wqkvb;

    convert_bf16<<<dim3(2048), 256, 0, stream>>>(x, xb, 2097152);
    convert_bf16<<<dim3(3072), 256, 0, stream>>>(Wqkv_w, wqkvb, 3145728);
    convert_bf16<<<dim3(1024), 256, 0, stream>>>(out_w, outwb, 1048576);

    gemm_bt<0><<<dim3(48, 32), 256, 0, stream>>>(xb, wqkvb, Wqkv_b, rope, qTp, kTp, vTp);
    transpose_v<<<dim3(16, 128), 256, 0, stream>>>(vTp, vTt);
    attn_mfma<<<dim3(16, 128), 256, 0, stream>>>(qTp, kTp, vTt, ctx);
    gemm_bt<1><<<dim3(16, 32), 256, 0, stream>>>(ctx, outwb, out_b, rope, out, nullptr, nullptr);
}